// Round 7
// baseline (233.809 us; speedup 1.0000x reference)
//
#include <hip/hip_runtime.h>
#include <hip/hip_bf16.h>

#define BATCH 2
#define SEQ   2048
#define EMBED 1024
#define HEADS 16
#define HDIM  64
#define NBH   (BATCH*HEADS)

typedef __attribute__((ext_vector_type(8))) short short8;
typedef __attribute__((ext_vector_type(4))) float floatx4;
typedef unsigned short u16;
typedef unsigned int   u32;

#define LOG2E 1.4426950408889634f

// async global->LDS, 16B per lane. LDS dest must be wave-uniform base + lane*16.
__device__ __forceinline__ void async_cp16(const void* g, void* l) {
  __builtin_amdgcn_global_load_lds((const __attribute__((address_space(1))) void*)g,
                                   (__attribute__((address_space(3))) void*)l,
                                   16, 0, 0);
}

__device__ __forceinline__ u16 f2b(float f) {  // f32 -> bf16 RNE
  union { float f; u32 u; } x; x.f = f;
  return (u16)((x.u + 0x7fffu + ((x.u >> 16) & 1u)) >> 16);
}
__device__ __forceinline__ u32 pk2(float a, float b) {  // packed bf16x2
  __hip_bfloat162 t = __float22bfloat162_rn(make_float2(a, b));
  return *reinterpret_cast<u32*>(&t);
}
__device__ __forceinline__ float fexp2(float x) {  // 2^x, single v_exp_f32
#if __has_builtin(__builtin_amdgcn_exp2f)
  return __builtin_amdgcn_exp2f(x);
#else
  return __expf(x * 0.6931471805599453f);
#endif
}

// ---------------------------------------------------------------------------
// f32 -> bf16 conversion of x, qkv_w, out_w (region bounds block-aligned).
// ---------------------------------------------------------------------------
__global__ __launch_bounds__(256)
void cvt_all(const float* __restrict__ x, const float* __restrict__ wqkv,
             const float* __restrict__ wo,
             u16* __restrict__ xb, u16* __restrict__ wqkvb, u16* __restrict__ wob) {
  const size_t t = (size_t)blockIdx.x * 256 + threadIdx.x;   // float4 index
  const float* src; u16* dst; size_t off;
  if (t < 1048576) { src = x; dst = xb; off = t; }
  else if (t < 1048576 + 786432) { src = wqkv; dst = wqkvb; off = t - 1048576; }
  else { src = wo; dst = wob; off = t - (1048576 + 786432); }
  float4 v = *(const float4*)(src + off * 4);
  ushort4 o;
  o.x = f2b(v.x); o.y = f2b(v.y); o.z = f2b(v.z); o.w = f2b(v.w);
  *(ushort4*)(dst + off * 4) = o;
}

// ---------------------------------------------------------------------------
// Fused QKV GEMM v4: 256x256 tile (staging-BANDWIDTH fix). R5/R6 showed the
// 128^2 structure is bound by 12 MB/step of L2/L3 staging delivery (~4700
// cyc/step regardless of pipeline depth/barriers). 256^2 halves staged
// bytes per FLOP (total 384 -> 192 MB) — m248 (same K=1024): 655 TF vs our
// 410. Sync pattern is R5's verified 2-phase: stage-next -> ds_read+MFMA ->
// __syncthreads. 512 threads = 8 waves (2m x 4n), each wave owns 128x64.
// LDS 2 x (16+16) KB = 64 KB; acc 128 VGPR -> 1 block/CU, grid 192.
// Block map: XCD = bid&7 owns 2 m-panels (X slice 1 MB, L2-resident) x all
// 12 n-panels (W streams once per XCD).
// n-panels 0..7 (Q/K): swapped operands -> [bh][s][d] packed stores.
// n-panels 8..11 (V):  normal operands  -> V^T [bh][d][s] packed stores.
// ---------------------------------------------------------------------------
__global__ __launch_bounds__(512, 2)
void qkv_gemm(const u16* __restrict__ X, const u16* __restrict__ W,
              u16* __restrict__ q_ws, u16* __restrict__ k_ws,
              u16* __restrict__ vT_ws) {
  __shared__ u16 As[2][4][256][8];   // 16 KB per buf: [buf][k-chunk][row][8]
  __shared__ u16 Bs[2][4][256][8];
  const int tid  = threadIdx.x;
  const int lane = tid & 63, wv = tid >> 6;        // 8 waves
  const int l15  = lane & 15, quad = lane >> 4;
  const int wm = (wv >> 2) << 7;                   // 0 / 128
  const int wn = (wv & 3) << 6;                    // 0 / 64 / 128 / 192

  // block map: XCD(bid&7) -> 2 m-panels x all n-panels
  const int bid = blockIdx.x;
  const int xcd = bid & 7, idx = bid >> 3;         // idx 0..23
  const int mb = (xcd << 1) | (idx & 1);           // 0..15
  const int nb = idx >> 1;                         // 0..11
  const int m0 = mb << 8, n0 = nb << 8;
  const bool vpath = (n0 >= 2048);

  // staging: 1024 slots of 16 B per array, 2 per thread
  const int kb0 = tid >> 8, r0 = tid & 255;        // kb0 in {0,1}
  const int kb1 = kb0 + 2, r1 = r0;                // kb1 in {2,3}

  floatx4 acc[8][4];
#pragma unroll
  for (int i = 0; i < 8; ++i)
#pragma unroll
    for (int j = 0; j < 4; ++j) acc[i][j] = {0.f, 0.f, 0.f, 0.f};

#define QKV_STAGE(kt, buf)                                                        \
  do {                                                                            \
    const int k0_ = (kt) << 5;                                                    \
    async_cp16(X + (size_t)(m0 + r0) * EMBED + k0_ + kb0 * 8, &As[buf][kb0][r0][0]); \
    async_cp16(X + (size_t)(m0 + r1) * EMBED + k0_ + kb1 * 8, &As[buf][kb1][r1][0]); \
    async_cp16(W + (size_t)(n0 + r0) * EMBED + k0_ + kb0 * 8, &Bs[buf][kb0][r0][0]); \
    async_cp16(W + (size_t)(n0 + r1) * EMBED + k0_ + kb1 * 8, &Bs[buf][kb1][r1][0]); \
  } while (0)

  QKV_STAGE(0, 0);
  __syncthreads();

  if (!vpath) {
    for (int t = 0; t < 32; ++t) {
      const int cur = t & 1;
      if (t < 31) QKV_STAGE(t + 1, cur ^ 1);       // issue next BEFORE compute
      short8 af[8], bf[4];
#pragma unroll
      for (int i = 0; i < 8; ++i)
        af[i] = *(const short8*)&As[cur][quad][wm + i * 16 + l15][0];
#pragma unroll
      for (int j = 0; j < 4; ++j)
        bf[j] = *(const short8*)&Bs[cur][quad][wn + j * 16 + l15][0];
      __builtin_amdgcn_s_setprio(1);
#pragma unroll
      for (int i = 0; i < 8; ++i)
#pragma unroll
        for (int j = 0; j < 4; ++j)
          acc[i][j] = __builtin_amdgcn_mfma_f32_16x16x32_bf16(bf[j], af[i], acc[i][j], 0, 0, 0);
      __builtin_amdgcn_s_setprio(0);
      __syncthreads();                             // drain next (hidden)
    }

    // D: row = quad*4+r -> weight col (d); col = l15 -> X row (s)
#pragma unroll
    for (int i = 0; i < 8; ++i) {
      int mg = m0 + wm + i * 16 + l15;
      int b = mg >> 11, s = mg & 2047;
#pragma unroll
      for (int j = 0; j < 4; ++j) {
        int col0 = n0 + wn + j * 16 + (quad << 2);
        int c = col0 >> 10, hd = col0 & 1023;
        int h = hd >> 6, d0 = hd & 63;
        u16* dst = c ? k_ws : q_ws;
        uint2 w;
        w.x = pk2(acc[i][j][0], acc[i][j][1]);
        w.y = pk2(acc[i][j][2], acc[i][j][3]);
        *(uint2*)(dst + (((size_t)(b * HEADS + h)) * SEQ + s) * HDIM + d0) = w;
      }
    }
  } else {
    for (int t = 0; t < 32; ++t) {
      const int cur = t & 1;
      if (t < 31) QKV_STAGE(t + 1, cur ^ 1);
      short8 af[8], bf[4];
#pragma unroll
      for (int i = 0; i < 8; ++i)
        af[i] = *(const short8*)&As[cur][quad][wm + i * 16 + l15][0];
#pragma unroll
      for (int j = 0; j < 4; ++j)
        bf[j] = *(const short8*)&Bs[cur][quad][wn + j * 16 + l15][0];
      __builtin_amdgcn_s_setprio(1);
#pragma unroll
      for (int i = 0; i < 8; ++i)
#pragma unroll
        for (int j = 0; j < 4; ++j)
          acc[i][j] = __builtin_amdgcn_mfma_f32_16x16x32_bf16(af[i], bf[j], acc[i][j], 0, 0, 0);
      __builtin_amdgcn_s_setprio(0);
      __syncthreads();
    }

    // D: row = quad*4+r -> s (4 consecutive); col = l15 -> weight col (h,d)
#pragma unroll
    for (int i = 0; i < 8; ++i) {
      int mg0 = m0 + wm + i * 16 + (quad << 2);
      int b = mg0 >> 11, s0 = mg0 & 2047;
#pragma unroll
      for (int j = 0; j < 4; ++j) {
        int col = n0 + wn + j * 16 + l15;
        int hd = col & 1023;
        int h = hd >> 6, d = hd & 63;
        uint2 w;
        w.x = pk2(acc[i][j][0], acc[i][j][1]);
        w.y = pk2(acc[i][j][2], acc[i][j][3]);
        *(uint2*)(vT_ws + (((size_t)(b * HEADS + h)) * HDIM + d) * SEQ + s0) = w;
      }
    }
  }
#undef QKV_STAGE
}

// ---------------------------------------------------------------------------
// Flash attention v9: 32 q-rows per wave (K/V fragment amortization).
// (unchanged from R3/R5/R6 — passed, <63 µs)
// ---------------------------------------------------------------------------
__global__ __launch_bounds__(256, 2)
void attn_kernel(const u16* __restrict__ q_ws, const u16* __restrict__ k_ws,
                 const u16* __restrict__ vT_ws, const int* __restrict__ mask,
                 u16* __restrict__ ao) {
  __shared__ u16 Ks[8][64][8];     // 8 KB [d/8][t][8]
  __shared__ u16 Vt[8][64][8];     // 8 KB [t/8][d][8]
  __shared__ u16 Ps[4][32][68];    // 17 KB P^T [wave][q][t+pad4]
  __shared__ float mskf[SEQ];      // 8 KB whole-row mask shift table

  const int tid  = threadIdx.x;
  const int lane = tid & 63, wv = tid >> 6;
  const int l15  = lane & 15, quad = lane >> 4;
  const int bh = blockIdx.x;                 // x = bh -> XCD = bh%8 (L2 reuse)
  const int b  = bh >> 4, h = bh & 15;
  const int qrw = (blockIdx.y << 7) + (wv << 5);   // 32 q-rows per wave

  const u16* Qb  = q_ws  + (size_t)bh * SEQ * HDIM;
  const u16* Kb  = k_ws  + (size_t)bh * SEQ * HDIM;
  const u16* VbT = vT_ws + (size_t)bh * HDIM * SEQ;

  // per-thread staging coords (wave-uniform kb, lane-contig r)
  const int kb0 = tid >> 6, r0 = tid & 63;
  const int kb1 = (tid + 256) >> 6, r1 = tid & 63;

  // mask -> fixed-shift table, once per block
#pragma unroll
  for (int i = 0; i < 8; ++i) {
    int idx = (i << 8) + tid;
    mskf[idx] = mask[b * SEQ + idx] ? -12.0f : -1e30f;
  }

  // tile 0 -> LDS (async, linear dest)
  async_cp16(Kb + (size_t)r0 * HDIM + kb0 * 8, &Ks[kb0][r0][0]);
  async_cp16(Kb + (size_t)r1 * HDIM + kb1 * 8, &Ks[kb1][r1][0]);
  async_cp16(VbT + (size_t)r0 * SEQ + kb0 * 8, &Vt[kb0][r0][0]);
  async_cp16(VbT + (size_t)r1 * SEQ + kb1 * 8, &Vt[kb1][r1][0]);

  // Q B-frags, two q-halves: B[k=d=quad*8+j][n=q=qh*16+l15], pre-scaled 1/8
  short8 qf[2][2];
#pragma unroll
  for (int qh = 0; qh < 2; ++qh)
#pragma unroll
    for (int s = 0; s < 2; ++s) {
      short8 v = *(const short8*)(Qb + (size_t)(qrw + qh * 16 + l15) * HDIM + s * 32 + quad * 8);
#pragma unroll
      for (int e = 0; e < 8; ++e) {
        union { float f; u32 u; } x;
        x.u = ((u32)(u16)v[e]) << 16;
        x.f *= 0.125f;
        v[e] = (short)(x.u >> 16);
      }
      qf[qh][s] = v;
    }

  // tile 1 -> regs
  short8 k0r, k1r, v0r, v1r;
  k0r = *(const short8*)(Kb + (size_t)(64 + r0) * HDIM + kb0 * 8);
  k1r = *(const short8*)(Kb + (size_t)(64 + r1) * HDIM + kb1 * 8);
  v0r = *(const short8*)(VbT + (size_t)r0 * SEQ + 64 + kb0 * 8);
  v1r = *(const short8*)(VbT + (size_t)r1 * SEQ + 64 + kb1 * 8);

  float l_acc[2] = {0.f, 0.f};     // in-lane partial sums (scaled 2^-12)
  floatx4 O[4][2];
#pragma unroll
  for (int dt = 0; dt < 4; ++dt)
#pragma unroll
    for (int qh = 0; qh < 2; ++qh) O[dt][qh] = {0.f, 0.f, 0.f, 0.f};

  __syncthreads();                 // tile0 + mask table visible (one-time drain)

  for (int it = 0; it < SEQ / 64; ++it) {
    const int t0 = it << 6;

    // ---- [A] compute tile it ------------------------------------------
    // S^T = K·(Q/8)^T : D[t=nt*16+quad*4+r][q=qh*16+l15]; kf reused 2x
    floatx4 sc[4][2];
    __builtin_amdgcn_s_setprio(1);
#pragma unroll
    for (int nt = 0; nt < 4; ++nt) {
      sc[nt][0] = {0.f, 0.f, 0.f, 0.f};
      sc[nt][1] = {0.f, 0.f, 0.f, 0.f};
#pragma unroll
      for (int s = 0; s < 2; ++s) {
        short8 kf = *(const short8*)&Ks[s * 4 + quad][nt * 16 + l15][0];
        sc[nt][0] = __builtin_amdgcn_mfma_f32_16x16x32_bf16(kf, qf[0][s], sc[nt][0], 0, 0, 0);
        sc[nt][1] = __builtin_amdgcn_mfma_f32_16x16x32_bf16(kf, qf[1][s], sc[nt][1], 0, 0, 0);
      }
    }
    __builtin_amdgcn_s_setprio(0);

    // p = 2^(s*log2e + msk); in-lane l accumulation; packed bf16 P^T store
#pragma unroll
    for (int nt = 0; nt < 4; ++nt) {
      const float4 m4 = *(const float4*)&mskf[t0 + nt * 16 + (quad << 2)];
#pragma unroll
      for (int qh = 0; qh < 2; ++qh) {
        float pv[4];
#pragma unroll
        for (int r = 0; r < 4; ++r) {
          pv[r] = fexp2(fmaf(sc[nt][qh][r], LOG2E, (&m4.x)[r]));
          l_acc[qh] += pv[r];
        }
        uint2 w;
        w.x = pk2(pv[0], pv[1]); w.y = pk2(pv[2], pv[3]);
        *(uint2*)&Ps[wv][qh * 16 + l15][nt * 16 + (quad << 2)] = w;
      }
    }

    // O^T += V^T·P^T : A = Vt (m=d), B = Ps (n=q); vf reused 2x; wave-local
    __builtin_amdgcn_s_setprio(1);
#pragma unroll
    for (int tch = 0; tch < 2; ++tch) {
      short8 pf0 = *(const short8*)&Ps[wv][l15][tch * 32 + quad * 8];
      short8 pf1 = *(const short8*)&Ps[wv][16 + l15][tch * 32 + quad * 8];
#pragma unroll
      for (int dt = 0; dt < 4; ++dt) {
        short8 vf = *(const short8*)&Vt[tch * 4 + quad][dt * 16 + l15][0];
        O[dt][0] = __builtin_amdgcn_mfma_f32_16x16x32_bf16(vf, pf0, O[dt][0], 0, 0, 0);
        O[dt][1] = __builtin_amdgcn_mfma_f32_16x16x32_bf16(vf, pf1, O[dt][1], 0, 0, 0);
      }
    }
    __builtin_amdgcn_s_setprio(0);

    if (it < SEQ / 64 - 1) {
      // ---- [B] all waves done reading tile it
      __syncthreads();
      // ---- [C] commit staged tile it+1 (vmcnt wait = register dep)
      *(short8*)&Ks[kb0][r0][0] = k0r;
      *(short8*)&Ks[kb1][r1][0] = k1r;
      *(short8*)&Vt[kb0][r0][0] = v0r;
      *(short8*)&Vt[kb1][r1][0] = v1r;
      // ---- [D] prefetch tile it+2 into regs (stays in flight across [E])
      if (it < SEQ / 64 - 2) {
        const int tn = t0 + 128;
        k0r = *(const short8*)(Kb + (size_t)(tn + r0) * HDIM + kb0 * 8);
        k1r = *(const short8*)(Kb + (size_t)(tn + r1) * HDIM + kb1 * 8);
        v0r = *(const short8*)(VbT + (size_t)r0 * SEQ + tn + kb0 * 8);
        v1r = *(const short8*)(VbT + (size_t)r1 * SEQ + tn + kb1 * 8);
      }
      // ---- [E] ds_writes visible to all waves; vmcnt NOT drained
      __builtin_amdgcn_sched_barrier(0);
      asm volatile("s_waitcnt lgkmcnt(0)" ::: "memory");
      __builtin_amdgcn_s_barrier();
      __builtin_amdgcn_sched_barrier(0);
    }
  }

  // one final cross-quad l reduction per q-half (q = l15 in both layouts)
#pragma unroll
  for (int qh = 0; qh < 2; ++qh) {
    l_acc[qh] += __shfl_xor(l_acc[qh], 16);
    l_acc[qh] += __shfl_xor(l_acc[qh], 32);
  }
  const float inv0 = 1.f / l_acc[0];
  const float inv1 = 1.f / l_acc[1];

#pragma unroll
  for (int qh = 0; qh < 2; ++qh) {
    const float inv = qh ? inv1 : inv0;
    const size_t rowbase = ((size_t)(b * SEQ + qrw + qh * 16 + l15)) * EMBED + h * 64;
#pragma unroll
    for (int dt = 0; dt < 4; ++dt) {
      uint2 w;
      w.x = pk2(O[dt][qh][0] * inv, O[dt][qh][1] * inv);
      w.y = pk2(O[dt][qh][2] * inv, O[dt][qh][3] * inv);
      *(uint2*)(ao + rowbase + dt * 16 + (quad << 2)) = w;
    }
  }
}

// ---------------------------------------------------------------------------
// Output projection v4: 128x128 tile (BN 64->128): grid (8,32)=256 = 1/CU
// perfect packing; staged traffic 192->128 MB; per-XCD working set A 1MB +
// W 2MB fully L2-resident. Same 2-phase dbuf pattern as qkv. Swapped
// operands, float4 stores + bias.
// ---------------------------------------------------------------------------
__global__ __launch_bounds__(256, 2)
void proj_gemm(const u16* __restrict__ A, const u16* __restrict__ W,
               const float* __restrict__ bias, float* __restrict__ out) {
  __shared__ u16 As[2][4][128][8];   // 8 KB per buf
  __shared__ u16 Bs[2][4][128][8];
  const int tid  = threadIdx.x;
  const int lane = tid & 63, wv = tid >> 6;
  const int l15  = lane & 15, quad = lane >> 4;
  const int wm = (wv >> 1) << 6, wn = (wv & 1) << 6;

  // block map: XCD(bid&7) -> 4 m-panels x all 8 n-panels (A+W L2-resident)
  const int bid = blockIdx.x;
  const int xcd = bid & 7, idx = bid >> 3;         // idx 0..31
  const int mb = (xcd << 2) | (idx & 3);           // 0..31
  const int nb = idx >> 2;                         // 0..7
  const int m0 = mb << 7, n0 = nb << 7;

  // staging: 512 slots of 16 B per array, 2 per thread
  const int kb0 = tid >> 7, r0 = tid & 127;
  const int kb1 = kb0 + 2, r1 = r0;

  floatx4 acc[4][4];
#pragma unroll
  for (int i = 0; i < 4; ++i)
#pragma unroll
    for (int j = 0; j < 4; ++j) acc[i][j] = {0.f, 0.f, 0.f, 0.f};

#define PRJ_STAGE(kt, buf)                                                        \
  do {                                                                            \
    const int k0_ = (kt) << 5;                                                    \
    async_cp16(A + (size_t)(m0 + r0) * EMBED + k0_ + kb0 * 8, &As[buf][kb0][r0][0]); \
    async_cp16(A + (size_t)(m0 + r1) * EMBED + k0_ + kb1 * 8, &As[buf][kb1][r1][0]); \
    async_cp16(W + (size_t)(n0 + r0) * EMBED + k0_ + kb0 * 8, &Bs[buf][kb0][r0][0]); \
    async_cp16(W + (size_t)(n0 + r1) * EMBED + k0_ + kb1 * 8, &Bs[buf][kb1][r1][0]); \
  } while (0)

  PRJ_STAGE(0, 0);
  __syncthreads();

  for (int t = 0; t < 32; ++t) {
    const int cur = t & 1;
    if (t < 31) PRJ_STAGE(t + 1, cur ^ 1);
    short8 af[4], bf[4];
#pragma unroll
    for (int f = 0; f < 4; ++f) {
      af[f] = *(const short8*)&As[cur][quad][wm + f * 16 + l15][0];
      bf[f] = *(const short8*)&Bs[cur][quad][wn + f * 16 + l15][0];
    }
    __builtin_amdgcn_s_setprio(1);
#pragma unroll
    for (int i = 0; i < 4; ++i)
#pragma unroll
      for (int j = 0; j < 4; ++j)
        acc[i][j] = __builtin_amdgcn_mfma_f32_16x16x32_bf16(bf[j], af[i], acc[i][j], 0, 0, 0);
    __builtin_amdgcn_s_setprio(0);
    __syncthreads();
  }
#undef PRJ_STAGE

  // D: row = quad*4+r -> col (4 consecutive n); col = l15 -> m
#pragma unroll
  for (int i = 0; i < 4; ++i) {
    int m = m0 + wm + i * 16 + l15;
#pragma unroll
    for (int j = 0; j < 4; ++j) {
      int col0 = n0 + wn + j * 16 + (quad << 2);
      float4 bv = *(const float4*)(bias + col0);
      float4 o;
      o.x = acc[i][j][0] + bv.x;
      o.y = acc[i][j][1] + bv.y;
      o.z = acc[i][j][2] + bv.z;
      o.w = acc[i][j][3] + bv.w;
      *(float4*)(out + (size_t)m * EMBED + col0) = o;
    }
  }
}

extern "C" void kernel_launch(void* const* d_in, const int* in_sizes, int n_in,
                              void* d_out, int out_size, void* d_ws, size_t ws_size,
                              hipStream_t stream) {
  const float* x     = (const float*)d_in[0];
  const int*   mask  = (const int*)d_in[1];
  const float* qkv_w = (const float*)d_in[2];
  const float* out_w = (const float*)d_in[3];
  const float* out_b = (const float*)d_in[4];
  float* out = (float*)d_out;

  const size_t per = (size_t)NBH * SEQ * HDIM;      // 4,194,304 elems
  u16* xb    = (u16*)d_ws;                          // 4,194,304
  u16* wqkvb = xb + 4194304;                        // 3,145,728
  u16* wob   = wqkvb + 3145728;                     // 1,048,576
  u16* q_ws  = wob + 1048576;
  u16* k_ws  = q_ws + per;
  u16* vT_ws = k_ws + per;                          // V^T [bh][d][s]
  u16* ao    = vT_ws + per;                         // 4096 x 1024

  cvt_all<<<8192, 256, 0, stream>>>(x, qkv_w, out_w, xb, wqkvb, wob);
  qkv_gemm<<<192, 512, 0, stream>>>(xb, wqkvb, q_ws, k_ws, vT_ws);
  // x = bh (XCD = bh%8, L2-resident K/V); y = q-chunk of 128 rows
  attn_kernel<<<dim3(NBH, SEQ / 128), 256, 0, stream>>>(q_ws, k_ws, vT_ws, mask, ao);
  proj_gemm<<<256, 256, 0, stream>>>(ao, wob, out_b, out);
}